// Round 3
// baseline (428.420 us; speedup 1.0000x reference)
//
#include <hip/hip_runtime.h>
#include <stdint.h>

#define LAMBDA_COORD 5.0f
#define LAMBDA_NOOBJ 0.5f

__global__ void zero_out_kernel(float* out) { out[0] = 0.0f; }

// Loss for one cell. p/t are constant-index views into SROA'd register
// arrays. NO dynamic indexing anywhere (dynamic idx -> scratch spill).
__device__ __forceinline__ float cell_loss(const float* __restrict__ p,
                                           const float* __restrict__ t) {
    float obj   = (t[4] > 0.0f)  ? 1.0f : 0.0f;
    float noobj = (t[4] == 0.0f) ? 1.0f : 0.0f;

    // IoU of both pred boxes vs target box; divide only feeds a compare.
    float ltx0 = fmaxf(p[0], t[0]), lty0 = fmaxf(p[1], t[1]);
    float rbx0 = fminf(p[2], t[2]), rby0 = fminf(p[3], t[3]);
    float inter0 = fmaxf(rbx0 - ltx0, 0.0f) * fmaxf(rby0 - lty0, 0.0f);
    float a10 = (p[2] - p[0]) * (p[3] - p[1]);

    float ltx1 = fmaxf(p[5], t[0]), lty1 = fmaxf(p[6], t[1]);
    float rbx1 = fminf(p[7], t[2]), rby1 = fminf(p[8], t[3]);
    float inter1 = fmaxf(rbx1 - ltx1, 0.0f) * fmaxf(rby1 - lty1, 0.0f);
    float a11 = (p[7] - p[5]) * (p[8] - p[6]);

    float a2 = (t[2] - t[0]) * (t[3] - t[1]);
    float iou0 = __fdividef(inter0, a10 + a2 - inter0);
    float iou1 = __fdividef(inter1, a11 + a2 - inter1);
    bool c0 = (iou0 >= iou1);   // jnp.argmax ties -> box 0

    // Constant-index ternaries (v_cndmask); every subscript literal.
    float px = c0 ? p[0] : p[5];
    float py = c0 ? p[1] : p[6];
    float pw = c0 ? p[2] : p[7];
    float ph = c0 ? p[3] : p[8];
    float pc = c0 ? p[4] : p[9];
    float tx = c0 ? t[0] : t[5];
    float ty = c0 ? t[1] : t[6];
    float tw = c0 ? t[2] : t[7];
    float th = c0 ? t[3] : t[8];
    float tc = c0 ? t[4] : t[9];

    float dx = px - tx, dy = py - ty;
    float l1 = dx * dx + dy * dy;
    float sw = sqrtf(pw) - sqrtf(tw);
    float sh = sqrtf(ph) - sqrtf(th);
    float l2 = sw * sw + sh * sh;
    float dc = pc - tc;
    float conf = dc * dc;

    float cls = 0.0f;
#pragma unroll
    for (int c = 10; c < 30; ++c) {
        float d = p[c] - t[c];
        cls += d * d;
    }

    return LAMBDA_COORD * (l1 + l2) * obj
         + conf * obj
         + LAMBDA_NOOBJ * conf * noobj
         + cls * obj;
}

// Per-wave chunk: 64 cells * 30 floats * 2 arrays = 3840 floats = 15,360 B
// = 15 coalesced float4 loads/lane (1 KB per instruction across the wave).
// Wave-private LDS region: [1920 pred floats][1920 targ floats], linear.
#define WAVE_F 3840

// Persistent + T14 async-split staging via REGULAR vector loads (not LDS-DMA):
//   issue 15 global_load_dwordx4 (chunk k+1) -> ds_read chunk k -> compute k
//   -> vmcnt(0) -> ds_write chunk k+1 -> loop.
// Discriminates whether the ~3 TB/s delivered plateau is the LDS-DMA path
// (regular-return path then breaks through) or a chip-level read ceiling.
__global__ __launch_bounds__(256, 2) void yolo_loss_kernel(
    const float* __restrict__ pred,
    const float* __restrict__ targ,
    float* __restrict__ out,
    int ncells)
{
    __shared__ __align__(16) float lds[4 * WAVE_F];   // 61,440 B -> 2 blocks/CU
    __shared__ float wsum[4];

    const int lane = threadIdx.x & 63;
    const int wid  = threadIdx.x >> 6;

    char* lb = (char*)&lds[wid * WAVE_F];

    const int nchunks = ncells >> 6;                  // 25,088 (exact)
    const int wstride = gridDim.x << 2;               // total waves = 2048
    int c = (blockIdx.x << 2) + wid;                  // global wave id

    const char* pb = (const char*)pred;
    const char* tb = (const char*)targ;

    float4 g[15];                                     // staging regs, 60 VGPRs

    // 15 coalesced dwordx4 loads for chunk cc: float4 slot f = r*64+lane;
    // f<480 -> pred, else targ (address-select, single load per slot).
    auto issue_loads = [&](int cc) {
        const size_t base = (size_t)cc * 7680;        // bytes into each array
#pragma unroll
        for (int r = 0; r < 15; ++r) {
            int f = r * 64 + lane;
            const char* src = ((f < 480) ? pb + base + (size_t)f * 16
                                         : tb + base + (size_t)(f - 480) * 16);
            g[r] = *(const float4*)src;
        }
    };
    // Linear write-back: slot f at LDS byte f*16 (conflict-free stride-1).
    auto write_lds = [&]() {
        float4* l4 = (float4*)lb;
#pragma unroll
        for (int r = 0; r < 15; ++r) l4[r * 64 + lane] = g[r];
    };

    float loss = 0.0f;

    if (c < nchunks) {                                // prologue: fill LDS
        issue_loads(c);
        asm volatile("s_waitcnt vmcnt(0)" ::: "memory");
        write_lds();
        asm volatile("s_waitcnt lgkmcnt(0)" ::: "memory");
    }

    while (c < nchunks) {
        int cn = c + wstride;
        if (cn < nchunks) issue_loads(cn);            // next chunk in flight

        // Drain LDS -> registers (15+15 ds_read_b64, lane stride 120 B,
        // 4-way conflict ~= 32 extra cy/chunk, off the critical path).
        float2 pv[15], tv[15];
        const float2* p2 = (const float2*)(lb + lane * 120);
        const float2* t2 = (const float2*)(lb + 7680 + lane * 120);
#pragma unroll
        for (int k = 0; k < 15; ++k) pv[k] = p2[k];
#pragma unroll
        for (int k = 0; k < 15; ++k) tv[k] = t2[k];
        asm volatile("s_waitcnt lgkmcnt(0)" ::: "memory");

        // Compute overlaps the in-flight global loads.
        loss += cell_loss((const float*)pv, (const float*)tv);

        if (cn < nchunks) {
            asm volatile("s_waitcnt vmcnt(0)" ::: "memory");
            write_lds();                              // wave-private: no barrier
            asm volatile("s_waitcnt lgkmcnt(0)" ::: "memory");
        }
        c = cn;
    }

    // Wave-64 butterfly reduction, then cross-wave via LDS, one atomic/block.
#pragma unroll
    for (int off = 32; off > 0; off >>= 1)
        loss += __shfl_down(loss, off, 64);

    if (lane == 0) wsum[wid] = loss;
    __syncthreads();
    if (threadIdx.x == 0) {
        atomicAdd(out, wsum[0] + wsum[1] + wsum[2] + wsum[3]);
    }
}

extern "C" void kernel_launch(void* const* d_in, const int* in_sizes, int n_in,
                              void* d_out, int out_size, void* d_ws, size_t ws_size,
                              hipStream_t stream) {
    const float* pred = (const float*)d_in[0];
    const float* targ = (const float*)d_in[1];
    float* out = (float*)d_out;

    int ncells = in_sizes[0] / 30;   // 1,605,632 (exact; divisible by 64)
    int grid = 512;                  // 2 blocks/CU * 256 CUs, persistent

    zero_out_kernel<<<1, 1, 0, stream>>>(out);
    yolo_loss_kernel<<<grid, 256, 0, stream>>>(pred, targ, out, ncells);
}

// Round 4
// 371.018 us; speedup vs baseline: 1.1547x; 1.1547x over previous
//
#include <hip/hip_runtime.h>
#include <stdint.h>

#define LAMBDA_COORD 5.0f
#define LAMBDA_NOOBJ 0.5f

__global__ void zero_out_kernel(float* out) { out[0] = 0.0f; }

// Loss for one cell. p/t are constant-index views into SROA'd register
// arrays. NO dynamic indexing anywhere (dynamic idx -> scratch spill).
__device__ __forceinline__ float cell_loss(const float* __restrict__ p,
                                           const float* __restrict__ t) {
    float obj   = (t[4] > 0.0f)  ? 1.0f : 0.0f;
    float noobj = (t[4] == 0.0f) ? 1.0f : 0.0f;

    // IoU of both pred boxes vs target box; divide only feeds a compare.
    float ltx0 = fmaxf(p[0], t[0]), lty0 = fmaxf(p[1], t[1]);
    float rbx0 = fminf(p[2], t[2]), rby0 = fminf(p[3], t[3]);
    float inter0 = fmaxf(rbx0 - ltx0, 0.0f) * fmaxf(rby0 - lty0, 0.0f);
    float a10 = (p[2] - p[0]) * (p[3] - p[1]);

    float ltx1 = fmaxf(p[5], t[0]), lty1 = fmaxf(p[6], t[1]);
    float rbx1 = fminf(p[7], t[2]), rby1 = fminf(p[8], t[3]);
    float inter1 = fmaxf(rbx1 - ltx1, 0.0f) * fmaxf(rby1 - lty1, 0.0f);
    float a11 = (p[7] - p[5]) * (p[8] - p[6]);

    float a2 = (t[2] - t[0]) * (t[3] - t[1]);
    float iou0 = __fdividef(inter0, a10 + a2 - inter0);
    float iou1 = __fdividef(inter1, a11 + a2 - inter1);
    bool c0 = (iou0 >= iou1);   // jnp.argmax ties -> box 0

    // Constant-index ternaries (v_cndmask); every subscript literal.
    float px = c0 ? p[0] : p[5];
    float py = c0 ? p[1] : p[6];
    float pw = c0 ? p[2] : p[7];
    float ph = c0 ? p[3] : p[8];
    float pc = c0 ? p[4] : p[9];
    float tx = c0 ? t[0] : t[5];
    float ty = c0 ? t[1] : t[6];
    float tw = c0 ? t[2] : t[7];
    float th = c0 ? t[3] : t[8];
    float tc = c0 ? t[4] : t[9];

    float dx = px - tx, dy = py - ty;
    float l1 = dx * dx + dy * dy;
    float sw = sqrtf(pw) - sqrtf(tw);
    float sh = sqrtf(ph) - sqrtf(th);
    float l2 = sw * sw + sh * sh;
    float dc = pc - tc;
    float conf = dc * dc;

    float cls = 0.0f;
#pragma unroll
    for (int c = 10; c < 30; ++c) {
        float d = p[c] - t[c];
        cls += d * d;
    }

    return LAMBDA_COORD * (l1 + l2) * obj
         + conf * obj
         + LAMBDA_NOOBJ * conf * noobj
         + cls * obj;
}

// Per-wave chunk: 64 cells * 30 floats * 2 arrays = 3840 floats = 15,360 B
// = exactly 15 rounds of global_load_lds x16 (64 lanes * 16 B).
// Layout: [1920 pred floats][1920 targ floats], linear (LDS dest of
// global_load_lds is wave-uniform base + lane*16 -> must be linear).
#define WAVE_F 3840

// Pressure-sweep variant of the round-2 pipeline: 1-wave (64T) blocks with
// 15,360 B LDS each -> 10 blocks/CU (LDS-capped), i.e. 10 independent DMA
// issue streams and ~150 KB in flight per CU (vs 8 streams / 120 KB).
// Wave-private LDS -> zero __syncthreads; pipeline:
//   vmcnt(0) -> ds_read chunk k -> lgkmcnt(0) -> issue chunk k+stride -> compute k.
__global__ __launch_bounds__(64, 1) void yolo_loss_kernel(
    const float* __restrict__ pred,
    const float* __restrict__ targ,
    float* __restrict__ out,
    int ncells)
{
    __shared__ __align__(16) float lds[WAVE_F];     // 15,360 B/block

    const int lane = threadIdx.x;                   // 0..63, one wave per block

    const char* pb = (const char*)pred;
    const char* tb = (const char*)targ;
    char* lb = (char*)lds;

    const int nchunks = ncells >> 6;                // 25,088 (ncells % 64 == 0)
    const int stride  = gridDim.x;                  // 2560 persistent waves
    int c = blockIdx.x;

    // Issue the 15 staging loads for chunk cc. Per-lane GLOBAL address
    // handles the pred/targ split; LDS destination is linear.
    auto issue_chunk = [&](int cc) {
        const size_t base = (size_t)cc * 7680;      // bytes into each array
#pragma unroll
        for (int r = 0; r < 15; ++r) {
            int f = r * 64 + lane;                  // float4 slot 0..959
            const char* src = (f < 480) ? pb + base + (size_t)f * 16
                                        : tb + base + (size_t)(f - 480) * 16;
            __builtin_amdgcn_global_load_lds(
                (const __attribute__((address_space(1))) uint32_t*)src,
                (__attribute__((address_space(3))) uint32_t*)(lb + r * 1024),
                16, 0, 0);
        }
    };

    float loss = 0.0f;

    if (c < nchunks) issue_chunk(c);                // prologue prefetch

    while (c < nchunks) {
        // Chunk c has landed in this wave's (private) LDS.
        asm volatile("s_waitcnt vmcnt(0)" ::: "memory");

        // Drain LDS -> registers (15+15 ds_read_b64, lane stride 120 B,
        // 4-way bank conflict, off the critical path).
        float2 pv[15], tv[15];
        const float2* p2 = (const float2*)(lb + lane * 120);
        const float2* t2 = (const float2*)(lb + 7680 + lane * 120);
#pragma unroll
        for (int k = 0; k < 15; ++k) pv[k] = p2[k];
#pragma unroll
        for (int k = 0; k < 15; ++k) tv[k] = t2[k];
        // Reads must complete before next chunk's DMA overwrites LDS.
        asm volatile("s_waitcnt lgkmcnt(0)" ::: "memory");

        int cn = c + stride;
        if (cn < nchunks) issue_chunk(cn);          // next chunk in flight

        // Compute overlaps the in-flight loads.
        loss += cell_loss((const float*)pv, (const float*)tv);

        c = cn;
    }

    // Wave-64 butterfly reduction; one atomic per wave (2560 total).
#pragma unroll
    for (int off = 32; off > 0; off >>= 1)
        loss += __shfl_down(loss, off, 64);
    if (lane == 0) atomicAdd(out, loss);
}

extern "C" void kernel_launch(void* const* d_in, const int* in_sizes, int n_in,
                              void* d_out, int out_size, void* d_ws, size_t ws_size,
                              hipStream_t stream) {
    const float* pred = (const float*)d_in[0];
    const float* targ = (const float*)d_in[1];
    float* out = (float*)d_out;

    int ncells = in_sizes[0] / 30;   // 1,605,632 (exact; divisible by 64)
    int grid = 2560;                 // 10 blocks/CU * 256 CUs, persistent

    zero_out_kernel<<<1, 1, 0, stream>>>(out);
    yolo_loss_kernel<<<grid, 64, 0, stream>>>(pred, targ, out, ncells);
}